// Round 1
// baseline (162.263 us; speedup 1.0000x reference)
//
#include <hip/hip_runtime.h>
#include <stdint.h>

// Bert4Argument R8: decompose out = seq·W1 (gathered, K=768 GEMM)
//                       + pe_logits[l-pos+256]   (precomputed 513x208)
//                       + ce_logits[l==pos?frame:0] (precomputed 201x208, bias folded)
// MFMA work 19.3 -> 5.4 GFLOP; prep seq-roundtrip (74 MB) eliminated; A converted
// f32->bf16 inline with issue-early reg staging; B dma16 from packed bf16 W.

typedef __attribute__((ext_vector_type(8))) short short8;
typedef __attribute__((ext_vector_type(4))) float f32x4;

#define AS1 __attribute__((address_space(1)))
#define AS3 __attribute__((address_space(3)))

// ---- workspace layout ----
// Wp (bf16, 13 tiles): [t][kb8 0..287][n16][8]  -> 479232 shorts (958464 B)
// pe_logits f32 [528][208] at float offset 239616
// ce_logits f32 [208][208] at float offset 349440  (bias folded in)
#define TILE_STRIDE 36864
#define NWPK_G     59904      // 13*288*16 pack units
#define NWPK_BLK   234        // 59904/256
#define NLOG_BLK   46         // 33 pe-blocks + 13 ce-blocks
#define PEL_OFF_F  239616
#define CEL_OFF_F  349440
#define WS_NEED_B  1570816

__device__ __forceinline__ unsigned short f2bf(float f) {
    union { float f; unsigned int u; } v; v.f = f;
    unsigned int u = v.u;
    return (unsigned short)((u + 0x7fffu + ((u >> 16) & 1u)) >> 16);
}

__device__ __forceinline__ short8 pack8(f32x4 a, f32x4 b) {
    short8 r;
    r[0] = (short)f2bf(a.x); r[1] = (short)f2bf(a.y);
    r[2] = (short)f2bf(a.z); r[3] = (short)f2bf(a.w);
    r[4] = (short)f2bf(b.x); r[5] = (short)f2bf(b.y);
    r[6] = (short)f2bf(b.z); r[7] = (short)f2bf(b.w);
    return r;
}

__device__ __forceinline__ void dma16(const unsigned short* g, AS3 unsigned short* l) {
    __builtin_amdgcn_global_load_lds((AS1 const unsigned int*)g,
                                     (AS3 unsigned int*)l, 16, 0, 0);
}

// ---------------------------------------------------------------------------
// prep: blocks [0,234): pack W f32 [200][2304] -> bf16 13-tile layout (rows>=200 zero)
//       blocks [234,280): small GEMMs pe_logits / ce_logits (W read f32 inline,
//       no dependency on the pack blocks). ce_logits gets bias folded in.
// ---------------------------------------------------------------------------
__global__ __launch_bounds__(256) void prep_kernel(
    const float* __restrict__ pe,
    const float* __restrict__ ce,
    const float* __restrict__ W,
    const float* __restrict__ bias,
    unsigned short* __restrict__ ws)
{
    if (blockIdx.x < NWPK_BLK) {
        // ---- W pack: g = ((t*288 + kb8)*16 + n) ----
        const int g   = blockIdx.x * 256 + threadIdx.x;     // < 59904 exactly
        const int n   = g & 15;
        const int kb8 = (g >> 4) % 288;
        const int t   = g / 4608;
        const int row = t * 16 + n;
        const int col = kb8 * 8;
        f32x4 a = {0.f, 0.f, 0.f, 0.f}, b = {0.f, 0.f, 0.f, 0.f};
        if (row < 200) {
            const float* p = W + (size_t)row * 2304 + col;
            a = *(const f32x4*)p;
            b = *(const f32x4*)(p + 4);
        }
        *(short8*)(ws + (size_t)g * 8) = pack8(a, b);
        return;
    }

    // ---- logits blocks: 16 output rows x 208 cols x K=768 each ----
    const int bb   = blockIdx.x - NWPK_BLK;
    const int w    = threadIdx.x >> 6;
    const int lane = threadIdx.x & 63;
    const int n16  = lane & 15;
    const int quad = lane >> 4;

    float* wsF = (float*)ws;
    int row0, nrows, koff;
    const float* A;
    float* outL;
    bool isCe;
    if (bb < 33) { isCe = false; row0 = bb * 16;        nrows = 513; koff = 768;  A = pe; outL = wsF + PEL_OFF_F; }
    else         { isCe = true;  row0 = (bb - 33) * 16; nrows = 201; koff = 1536; A = ce; outL = wsF + CEL_OFF_F; }

    int arow = row0 + n16; if (arow >= nrows) arow = nrows - 1;   // clamp: junk rows never read
    const float* abase = A + (size_t)arow * 768 + quad * 8;

    f32x4 acc[4];
    const float* wbase[4];
    bool wok[4];
    int colU[4];
#pragma unroll
    for (int u = 0; u < 4; ++u) {
        const int t   = w + 4 * u;
        const int col = t * 16 + n16;
        colU[u] = col;
        wok[u]  = (t < 13) && (col < 200);
        const float bv = (isCe && wok[u]) ? bias[col] : 0.0f;
        acc[u] = (f32x4){bv, bv, bv, bv};
        wbase[u] = W + (size_t)(wok[u] ? col : 0) * 2304 + koff + quad * 8;
    }

    for (int ks = 0; ks < 24; ++ks) {
        const float* ap = abase + ks * 32;
        short8 af = pack8(*(const f32x4*)ap, *(const f32x4*)(ap + 4));
#pragma unroll
        for (int u = 0; u < 4; ++u) {
            if (w + 4 * u < 13) {
                short8 bf = {0, 0, 0, 0, 0, 0, 0, 0};
                if (wok[u]) {
                    const float* wp = wbase[u] + ks * 32;
                    bf = pack8(*(const f32x4*)wp, *(const f32x4*)(wp + 4));
                }
                acc[u] = __builtin_amdgcn_mfma_f32_16x16x32_bf16(af, bf, acc[u], 0, 0, 0);
            }
        }
    }

    const int rb = row0 + quad * 4;
#pragma unroll
    for (int u = 0; u < 4; ++u) {
        if (w + 4 * u < 13) {
#pragma unroll
            for (int r = 0; r < 4; ++r)
                outL[(size_t)(rb + r) * 208 + colU[u]] = acc[u][r];
        }
    }
}

// ---------------------------------------------------------------------------
// Main GEMM: seq-part only, K=768 (6 chunks of 128). grid 512 x 512 thr.
// mblk = blockIdx>>1 (64 rows), h = blockIdx&1 (h=0: tiles 0..6, h=1: 7..12)
// - interleaved h keeps both blocks of an mblk temporally adjacent (L2 dedup of A)
// A: gathered f32 loads issued one chunk EARLY (latency under MFMA), cvt->ds_write.
//    16 slabs (fm 0..3, ks 0..3), addr ((fm*4+ks)*64+lane)*8.
// B: dma16 from Wp, ntiles*4 KB/chunk, local tile t at lds+8192+t*2048.
// LDS 44 KB, __launch_bounds__(512,4) -> 2 blocks/CU.
// Epilogue: + pe_logits[rel,col] + ce_logits[cls,col] (bias inside), write f32.
// ---------------------------------------------------------------------------
__global__ __launch_bounds__(512, 4) void gemm_kernel(
    const unsigned short* __restrict__ ws,
    const float* __restrict__ seq,
    const int*   __restrict__ head,
    const int*   __restrict__ frame,
    const int*   __restrict__ pos,
    float* __restrict__ out)
{
    __shared__ unsigned short lds[8192 + 7 * 2048];   // 45056 B

    const unsigned short* Wp = ws;
    const float* wsF = (const float*)ws;
    const float* peL = wsF + PEL_OFF_F;
    const float* ceL = wsF + CEL_OFF_F;

    const int tid  = threadIdx.x;
    const int wave = tid >> 6;
    const int lane = tid & 63;
    const int n16  = lane & 15;
    const int quad = lane >> 4;

    const int mblk   = blockIdx.x >> 1;
    const int h      = blockIdx.x & 1;
    const int ntiles = h ? 6 : 7;
    const int tb     = h * 7;

    const int i       = mblk >> 2;
    const int pos_i   = pos[i];
    const int frame_i = frame[i];

    // ---- A staging: wave stages slabs (smf, skb) and (smf, skb+1) ----
    const int smf = wave & 3;
    const int skb = (wave >> 2) * 2;
    const int srow = mblk * 64 + smf * 16 + n16;
    const int hi   = head[srow];
    const float* aP = seq + ((size_t)i * 256 + hi) * 768 + skb * 32 + quad * 8;
    unsigned short* aDst0 = (unsigned short*)lds + ((smf * 4 + skb) * 64 + lane) * 8;
    unsigned short* aDst1 = aDst0 + 512;

    // ---- compute partition ----
    const int p = wave & 1;
    const int q = wave >> 1;
    const unsigned short* aRd0 = lds + (2 * p) * 2048 + lane * 8;
    const unsigned short* aRd1 = aRd0 + 2048;
    const unsigned short* bRd[2];
    bool uok[2];
#pragma unroll
    for (int u = 0; u < 2; ++u) {
        const int t = q + 4 * u;
        uok[u] = (t < ntiles);
        bRd[u] = lds + 8192 + (uok[u] ? t : 0) * 2048 + quad * 128 + n16 * 8;
    }

    f32x4 acc[2][2];
#pragma unroll
    for (int f = 0; f < 2; ++f)
#pragma unroll
        for (int u = 0; u < 2; ++u)
            acc[f][u] = (f32x4){0.f, 0.f, 0.f, 0.f};

    // prologue: issue A loads for chunk 0
    f32x4 a00 = *(const f32x4*)(aP);
    f32x4 a01 = *(const f32x4*)(aP + 4);
    f32x4 a10 = *(const f32x4*)(aP + 32);
    f32x4 a11 = *(const f32x4*)(aP + 36);

    for (int cc = 0; cc < 6; ++cc) {
        // stage A (regs -> LDS) and B (dma16)
        *(short8*)aDst0 = pack8(a00, a01);
        *(short8*)aDst1 = pack8(a10, a11);
        const int units = ntiles * 4;
        for (int un = wave; un < units; un += 8) {
            const int t = un >> 2, part = un & 3;
            dma16(Wp + (size_t)(tb + t) * TILE_STRIDE + cc * 2048 + part * 512 + lane * 8,
                  (AS3 unsigned short*)lds + 8192 + t * 2048 + part * 512 + lane * 8);
        }
        __syncthreads();
        // issue next chunk's A loads early: latency hides under MFMA below
        if (cc < 5) {
            const float* ap = aP + (cc + 1) * 128;
            a00 = *(const f32x4*)(ap);
            a01 = *(const f32x4*)(ap + 4);
            a10 = *(const f32x4*)(ap + 32);
            a11 = *(const f32x4*)(ap + 36);
        }
#pragma unroll
        for (int ks = 0; ks < 4; ++ks) {
            short8 a0 = *(const short8*)(aRd0 + ks * 512);
            short8 a1 = *(const short8*)(aRd1 + ks * 512);
#pragma unroll
            for (int u = 0; u < 2; ++u) {
                if (uok[u]) {
                    short8 bf = *(const short8*)(bRd[u] + ks * 512);
                    acc[0][u] = __builtin_amdgcn_mfma_f32_16x16x32_bf16(a0, bf, acc[0][u], 0, 0, 0);
                    acc[1][u] = __builtin_amdgcn_mfma_f32_16x16x32_bf16(a1, bf, acc[1][u], 0, 0, 0);
                }
            }
        }
        __syncthreads();
    }

    // epilogue: C/D col = lane&15, row = quad*4 + r; add gathered logits
#pragma unroll
    for (int f = 0; f < 2; ++f) {
        const int rbase = mblk * 64 + (2 * p + f) * 16 + quad * 4;
#pragma unroll
        for (int u = 0; u < 2; ++u) {
            if (uok[u]) {
                const int col = (tb + q + 4 * u) * 16 + n16;
                if (col < 200) {
#pragma unroll
                    for (int r = 0; r < 4; ++r) {
                        const int row = rbase + r;
                        const int l   = row & 255;
                        const int rel = l - pos_i + 256;
                        const int cls = (l == pos_i) ? frame_i : 0;
                        out[(size_t)row * 200 + col] =
                            acc[f][u][r] + peL[(size_t)rel * 208 + col]
                                         + ceL[(size_t)cls * 208 + col];
                    }
                }
            }
        }
    }
}

// ---------------------------------------------------------------------------
// Fallback (no workspace): slow but correct, f32 W converted inline.
// ---------------------------------------------------------------------------
__global__ __launch_bounds__(256) void gemm_fallback(
    const float* __restrict__ seq, const float* __restrict__ pe,
    const float* __restrict__ ce, const float* __restrict__ Wf,
    const float* __restrict__ bias, const int* __restrict__ head,
    const int* __restrict__ frame, const int* __restrict__ pos,
    float* __restrict__ out)
{
    const int tid  = threadIdx.x;
    const int wave = tid >> 6;
    const int lane = tid & 63;
    const int n16  = lane & 15;
    const int quad = lane >> 4;

    const int mrow  = blockIdx.x * 16 + n16;
    const int i     = mrow >> 8;
    const int j     = mrow & 255;
    const int pos_i = pos[i];
    const int hi    = head[mrow];
    const int rel   = j - pos_i + 256;
    const int cls   = (j == pos_i) ? frame[i] : 0;

    const float* segs[3];
    segs[0] = seq + ((size_t)i * 256 + (size_t)hi) * 768 + quad * 8;
    segs[1] = pe + (size_t)rel * 768 + quad * 8;
    segs[2] = ce + (size_t)cls * 768 + quad * 8;

    const int ntl = (wave == 0) ? 4 : 3;
    f32x4 acc[4];
#pragma unroll
    for (int u = 0; u < 4; ++u) {
        const int t = wave + 4 * u;
        const int col = t * 16 + n16;
        const float bv = (t < 13 && col < 200) ? bias[col] : 0.0f;
        acc[u] = (f32x4){bv, bv, bv, bv};
    }

    for (int s = 0; s < 3; ++s) {
        const float* ap = segs[s];
#pragma unroll 2
        for (int kk = 0; kk < 768; kk += 32) {
            short8 afr = pack8(*(const f32x4*)(ap + kk), *(const f32x4*)(ap + kk + 4));
#pragma unroll
            for (int u = 0; u < 4; ++u) {
                if (u < ntl) {
                    const int t = wave + 4 * u;
                    const int row = t * 16 + n16;
                    short8 bfr = {0, 0, 0, 0, 0, 0, 0, 0};
                    if (row < 200) {
                        const float* qp = Wf + (size_t)row * 2304 + s * 768 + kk + quad * 8;
                        bfr = pack8(*(const f32x4*)qp, *(const f32x4*)(qp + 4));
                    }
                    acc[u] = __builtin_amdgcn_mfma_f32_16x16x32_bf16(afr, bfr, acc[u], 0, 0, 0);
                }
            }
        }
    }

    const int rbase = blockIdx.x * 16 + quad * 4;
#pragma unroll
    for (int u = 0; u < 4; ++u) {
        const int t = wave + 4 * u;
        if (t < 13) {
            const int col = t * 16 + n16;
            if (col < 200) {
#pragma unroll
                for (int r = 0; r < 4; ++r)
                    out[(size_t)(rbase + r) * 200 + col] = acc[u][r];
            }
        }
    }
}

// ---------------------------------------------------------------------------
extern "C" void kernel_launch(void* const* d_in, const int* in_sizes, int n_in,
                              void* d_out, int out_size, void* d_ws, size_t ws_size,
                              hipStream_t stream) {
    const float* seq  = (const float*)d_in[0];
    const float* pe   = (const float*)d_in[1];
    const float* ce   = (const float*)d_in[2];
    const float* W    = (const float*)d_in[3];
    const float* bias = (const float*)d_in[4];
    const int* head   = (const int*)d_in[5];
    const int* frame  = (const int*)d_in[6];
    const int* pos    = (const int*)d_in[7];
    float* out = (float*)d_out;

    if (d_ws != nullptr && ws_size >= (size_t)WS_NEED_B) {
        unsigned short* ws = (unsigned short*)d_ws;
        prep_kernel<<<NWPK_BLK + NLOG_BLK, 256, 0, stream>>>(pe, ce, W, bias, ws);
        gemm_kernel<<<512, 512, 0, stream>>>(ws, seq, head, frame, pos, out);
    } else {
        gemm_fallback<<<1024, 256, 0, stream>>>(seq, pe, ce, W, bias, head,
                                                frame, pos, out);
    }
}

// Round 2
// 127.995 us; speedup vs baseline: 1.2677x; 1.2677x over previous
//
#include <hip/hip_runtime.h>
#include <stdint.h>

// Bert4Argument R9: decompose out = seq·W1 (gathered, K=768 GEMM)
//                       + pe_logits[l-pos+256]   (precomputed 513x208)
//                       + ce_logits[l==pos?frame:0] (precomputed 201x208, bias folded)
// R8 regression fix: logits precompute was 46 blocks (1 wave/SIMD on 46 CUs,
// latency-bound, 54us). Now split rowblk(64) x ntile(16): 169 blocks, each wave
// owns one 16x16 output, 24-step K-loop. Predicted prep ~5us.

typedef __attribute__((ext_vector_type(8))) short short8;
typedef __attribute__((ext_vector_type(4))) float f32x4;

#define AS1 __attribute__((address_space(1)))
#define AS3 __attribute__((address_space(3)))

// ---- workspace layout ----
// Wp (bf16, 13 tiles): [t][kb8 0..287][n16][8]  -> 479232 shorts (958464 B)
// pe_logits f32 [528][208] at float offset 239616
// ce_logits f32 [208][208] at float offset 349440  (bias folded in)
#define TILE_STRIDE 36864
#define NWPK_BLK   234        // 59904/256 W-pack units
#define NT         13
#define NPE_RB     9          // 9*64 = 576 rows cover 513
#define NCE_RB     4          // 4*64 = 256 rows cover 201
#define NLOG_BLK   ((NPE_RB + NCE_RB) * NT)   // 169
#define PEL_OFF_F  239616
#define CEL_OFF_F  349440
#define WS_NEED_B  1570816

__device__ __forceinline__ unsigned short f2bf(float f) {
    union { float f; unsigned int u; } v; v.f = f;
    unsigned int u = v.u;
    return (unsigned short)((u + 0x7fffu + ((u >> 16) & 1u)) >> 16);
}

__device__ __forceinline__ short8 pack8(f32x4 a, f32x4 b) {
    short8 r;
    r[0] = (short)f2bf(a.x); r[1] = (short)f2bf(a.y);
    r[2] = (short)f2bf(a.z); r[3] = (short)f2bf(a.w);
    r[4] = (short)f2bf(b.x); r[5] = (short)f2bf(b.y);
    r[6] = (short)f2bf(b.z); r[7] = (short)f2bf(b.w);
    return r;
}

__device__ __forceinline__ void dma16(const unsigned short* g, AS3 unsigned short* l) {
    __builtin_amdgcn_global_load_lds((AS1 const unsigned int*)g,
                                     (AS3 unsigned int*)l, 16, 0, 0);
}

// ---------------------------------------------------------------------------
// prep: blocks [0,234): pack W f32 [200][2304] -> bf16 13-tile layout (rows>=200 zero)
//       blocks [234,403): logits GEMMs. Block = (rowblk of 64 rows) x (one n-tile).
//       Wave w owns 16x16 output: A rows rowblk*64+w*16+[0,16), cols t*16+[0,16).
//       W read f32 inline (no dependency on pack blocks). ce gets bias folded in.
// ---------------------------------------------------------------------------
__global__ __launch_bounds__(256) void prep_kernel(
    const float* __restrict__ pe,
    const float* __restrict__ ce,
    const float* __restrict__ W,
    const float* __restrict__ bias,
    unsigned short* __restrict__ ws)
{
    if (blockIdx.x < NWPK_BLK) {
        // ---- W pack: g = ((t*288 + kb8)*16 + n) ----
        const int g   = blockIdx.x * 256 + threadIdx.x;     // < 59904 exactly
        const int n   = g & 15;
        const int kb8 = (g >> 4) % 288;
        const int t   = g / 4608;
        const int row = t * 16 + n;
        const int col = kb8 * 8;
        f32x4 a = {0.f, 0.f, 0.f, 0.f}, b = {0.f, 0.f, 0.f, 0.f};
        if (row < 200) {
            const float* p = W + (size_t)row * 2304 + col;
            a = *(const f32x4*)p;
            b = *(const f32x4*)(p + 4);
        }
        *(short8*)(ws + (size_t)g * 8) = pack8(a, b);
        return;
    }

    // ---- logits blocks ----
    const int bb   = blockIdx.x - NWPK_BLK;
    const int w    = threadIdx.x >> 6;
    const int lane = threadIdx.x & 63;
    const int n16  = lane & 15;
    const int quad = lane >> 4;

    float* wsF = (float*)ws;
    int rowblk, t, nrows, koff;
    const float* A;
    float* outL;
    bool isCe;
    if (bb < NPE_RB * NT) {
        isCe = false; rowblk = bb / NT; t = bb % NT;
        nrows = 513; koff = 768;  A = pe; outL = wsF + PEL_OFF_F;
    } else {
        const int b2 = bb - NPE_RB * NT;
        isCe = true;  rowblk = b2 / NT; t = b2 % NT;
        nrows = 201; koff = 1536; A = ce; outL = wsF + CEL_OFF_F;
    }

    int arow = rowblk * 64 + w * 16 + n16;
    if (arow >= nrows) arow = nrows - 1;           // clamp: junk rows never read
    const float* abase = A + (size_t)arow * 768 + quad * 8;

    const int col  = t * 16 + n16;                 // may reach 207; cols>=200 junk
    const int wrow = (col < 200) ? col : 0;
    const float* wbase = W + (size_t)wrow * 2304 + koff + quad * 8;

    f32x4 acc;
    {
        const float bv = (isCe && col < 200) ? bias[col] : 0.0f;
        acc = (f32x4){bv, bv, bv, bv};
    }

#pragma unroll 4
    for (int ks = 0; ks < 24; ++ks) {
        const float* ap = abase + ks * 32;
        const float* wp = wbase + ks * 32;
        short8 af = pack8(*(const f32x4*)ap, *(const f32x4*)(ap + 4));
        short8 bf = pack8(*(const f32x4*)wp, *(const f32x4*)(wp + 4));
        acc = __builtin_amdgcn_mfma_f32_16x16x32_bf16(af, bf, acc, 0, 0, 0);
    }

    const int rb = rowblk * 64 + w * 16 + quad * 4;
#pragma unroll
    for (int r = 0; r < 4; ++r) {
        const int row = rb + r;
        if (row < nrows)
            outL[(size_t)row * 208 + col] = acc[r];
    }
}

// ---------------------------------------------------------------------------
// Main GEMM: seq-part only, K=768 (6 chunks of 128). grid 512 x 512 thr.
// mblk = blockIdx>>1 (64 rows), h = blockIdx&1 (h=0: tiles 0..6, h=1: 7..12)
// A: gathered f32 loads issued one chunk EARLY (latency under MFMA), cvt->ds_write.
//    16 slabs (fm 0..3, ks 0..3), addr ((fm*4+ks)*64+lane)*8.
// B: dma16 from Wp, ntiles*4 KB/chunk, local tile t at lds+8192+t*2048.
// LDS 44 KB, __launch_bounds__(512,4) -> 2 blocks/CU.
// Epilogue: + pe_logits[rel,col] + ce_logits[cls,col] (bias inside), write f32.
// ---------------------------------------------------------------------------
__global__ __launch_bounds__(512, 4) void gemm_kernel(
    const unsigned short* __restrict__ ws,
    const float* __restrict__ seq,
    const int*   __restrict__ head,
    const int*   __restrict__ frame,
    const int*   __restrict__ pos,
    float* __restrict__ out)
{
    __shared__ unsigned short lds[8192 + 7 * 2048];   // 45056 B

    const unsigned short* Wp = ws;
    const float* wsF = (const float*)ws;
    const float* peL = wsF + PEL_OFF_F;
    const float* ceL = wsF + CEL_OFF_F;

    const int tid  = threadIdx.x;
    const int wave = tid >> 6;
    const int lane = tid & 63;
    const int n16  = lane & 15;
    const int quad = lane >> 4;

    const int mblk   = blockIdx.x >> 1;
    const int h      = blockIdx.x & 1;
    const int ntiles = h ? 6 : 7;
    const int tb     = h * 7;

    const int i       = mblk >> 2;
    const int pos_i   = pos[i];
    const int frame_i = frame[i];

    // ---- A staging: wave stages slabs (smf, skb) and (smf, skb+1) ----
    const int smf = wave & 3;
    const int skb = (wave >> 2) * 2;
    const int srow = mblk * 64 + smf * 16 + n16;
    const int hi   = head[srow];
    const float* aP = seq + ((size_t)i * 256 + hi) * 768 + skb * 32 + quad * 8;
    unsigned short* aDst0 = (unsigned short*)lds + ((smf * 4 + skb) * 64 + lane) * 8;
    unsigned short* aDst1 = aDst0 + 512;

    // ---- compute partition ----
    const int p = wave & 1;
    const int q = wave >> 1;
    const unsigned short* aRd0 = lds + (2 * p) * 2048 + lane * 8;
    const unsigned short* aRd1 = aRd0 + 2048;
    const unsigned short* bRd[2];
    bool uok[2];
#pragma unroll
    for (int u = 0; u < 2; ++u) {
        const int t = q + 4 * u;
        uok[u] = (t < ntiles);
        bRd[u] = lds + 8192 + (uok[u] ? t : 0) * 2048 + quad * 128 + n16 * 8;
    }

    f32x4 acc[2][2];
#pragma unroll
    for (int f = 0; f < 2; ++f)
#pragma unroll
        for (int u = 0; u < 2; ++u)
            acc[f][u] = (f32x4){0.f, 0.f, 0.f, 0.f};

    // prologue: issue A loads for chunk 0
    f32x4 a00 = *(const f32x4*)(aP);
    f32x4 a01 = *(const f32x4*)(aP + 4);
    f32x4 a10 = *(const f32x4*)(aP + 32);
    f32x4 a11 = *(const f32x4*)(aP + 36);

    for (int cc = 0; cc < 6; ++cc) {
        // stage A (regs -> LDS) and B (dma16)
        *(short8*)aDst0 = pack8(a00, a01);
        *(short8*)aDst1 = pack8(a10, a11);
        const int units = ntiles * 4;
        for (int un = wave; un < units; un += 8) {
            const int t = un >> 2, part = un & 3;
            dma16(Wp + (size_t)(tb + t) * TILE_STRIDE + cc * 2048 + part * 512 + lane * 8,
                  (AS3 unsigned short*)lds + 8192 + t * 2048 + part * 512 + lane * 8);
        }
        __syncthreads();
        // issue next chunk's A loads early: latency hides under MFMA below
        if (cc < 5) {
            const float* ap = aP + (cc + 1) * 128;
            a00 = *(const f32x4*)(ap);
            a01 = *(const f32x4*)(ap + 4);
            a10 = *(const f32x4*)(ap + 32);
            a11 = *(const f32x4*)(ap + 36);
        }
#pragma unroll
        for (int ks = 0; ks < 4; ++ks) {
            short8 a0 = *(const short8*)(aRd0 + ks * 512);
            short8 a1 = *(const short8*)(aRd1 + ks * 512);
#pragma unroll
            for (int u = 0; u < 2; ++u) {
                if (uok[u]) {
                    short8 bf = *(const short8*)(bRd[u] + ks * 512);
                    acc[0][u] = __builtin_amdgcn_mfma_f32_16x16x32_bf16(a0, bf, acc[0][u], 0, 0, 0);
                    acc[1][u] = __builtin_amdgcn_mfma_f32_16x16x32_bf16(a1, bf, acc[1][u], 0, 0, 0);
                }
            }
        }
        __syncthreads();
    }

    // epilogue: C/D col = lane&15, row = quad*4 + r; add gathered logits
#pragma unroll
    for (int f = 0; f < 2; ++f) {
        const int rbase = mblk * 64 + (2 * p + f) * 16 + quad * 4;
#pragma unroll
        for (int u = 0; u < 2; ++u) {
            if (uok[u]) {
                const int col = (tb + q + 4 * u) * 16 + n16;
                if (col < 200) {
#pragma unroll
                    for (int r = 0; r < 4; ++r) {
                        const int row = rbase + r;
                        const int l   = row & 255;
                        const int rel = l - pos_i + 256;
                        const int cls = (l == pos_i) ? frame_i : 0;
                        out[(size_t)row * 200 + col] =
                            acc[f][u][r] + peL[(size_t)rel * 208 + col]
                                         + ceL[(size_t)cls * 208 + col];
                    }
                }
            }
        }
    }
}

// ---------------------------------------------------------------------------
// Fallback (no workspace): slow but correct, f32 W converted inline.
// ---------------------------------------------------------------------------
__global__ __launch_bounds__(256) void gemm_fallback(
    const float* __restrict__ seq, const float* __restrict__ pe,
    const float* __restrict__ ce, const float* __restrict__ Wf,
    const float* __restrict__ bias, const int* __restrict__ head,
    const int* __restrict__ frame, const int* __restrict__ pos,
    float* __restrict__ out)
{
    const int tid  = threadIdx.x;
    const int wave = tid >> 6;
    const int lane = tid & 63;
    const int n16  = lane & 15;
    const int quad = lane >> 4;

    const int mrow  = blockIdx.x * 16 + n16;
    const int i     = mrow >> 8;
    const int j     = mrow & 255;
    const int pos_i = pos[i];
    const int hi    = head[mrow];
    const int rel   = j - pos_i + 256;
    const int cls   = (j == pos_i) ? frame[i] : 0;

    const float* segs[3];
    segs[0] = seq + ((size_t)i * 256 + (size_t)hi) * 768 + quad * 8;
    segs[1] = pe + (size_t)rel * 768 + quad * 8;
    segs[2] = ce + (size_t)cls * 768 + quad * 8;

    const int ntl = (wave == 0) ? 4 : 3;
    f32x4 acc[4];
#pragma unroll
    for (int u = 0; u < 4; ++u) {
        const int t = wave + 4 * u;
        const int col = t * 16 + n16;
        const float bv = (t < 13 && col < 200) ? bias[col] : 0.0f;
        acc[u] = (f32x4){bv, bv, bv, bv};
    }

    for (int s = 0; s < 3; ++s) {
        const float* ap = segs[s];
#pragma unroll 2
        for (int kk = 0; kk < 768; kk += 32) {
            short8 afr = pack8(*(const f32x4*)(ap + kk), *(const f32x4*)(ap + kk + 4));
#pragma unroll
            for (int u = 0; u < 4; ++u) {
                if (u < ntl) {
                    const int t = wave + 4 * u;
                    const int row = t * 16 + n16;
                    short8 bfr = {0, 0, 0, 0, 0, 0, 0, 0};
                    if (row < 200) {
                        const float* qp = Wf + (size_t)row * 2304 + s * 768 + kk + quad * 8;
                        bfr = pack8(*(const f32x4*)qp, *(const f32x4*)(qp + 4));
                    }
                    acc[u] = __builtin_amdgcn_mfma_f32_16x16x32_bf16(afr, bfr, acc[u], 0, 0, 0);
                }
            }
        }
    }

    const int rbase = blockIdx.x * 16 + quad * 4;
#pragma unroll
    for (int u = 0; u < 4; ++u) {
        const int t = wave + 4 * u;
        if (t < 13) {
            const int col = t * 16 + n16;
            if (col < 200) {
#pragma unroll
                for (int r = 0; r < 4; ++r)
                    out[(size_t)(rbase + r) * 200 + col] = acc[u][r];
            }
        }
    }
}

// ---------------------------------------------------------------------------
extern "C" void kernel_launch(void* const* d_in, const int* in_sizes, int n_in,
                              void* d_out, int out_size, void* d_ws, size_t ws_size,
                              hipStream_t stream) {
    const float* seq  = (const float*)d_in[0];
    const float* pe   = (const float*)d_in[1];
    const float* ce   = (const float*)d_in[2];
    const float* W    = (const float*)d_in[3];
    const float* bias = (const float*)d_in[4];
    const int* head   = (const int*)d_in[5];
    const int* frame  = (const int*)d_in[6];
    const int* pos    = (const int*)d_in[7];
    float* out = (float*)d_out;

    if (d_ws != nullptr && ws_size >= (size_t)WS_NEED_B) {
        unsigned short* ws = (unsigned short*)d_ws;
        prep_kernel<<<NWPK_BLK + NLOG_BLK, 256, 0, stream>>>(pe, ce, W, bias, ws);
        gemm_kernel<<<512, 512, 0, stream>>>(ws, seq, head, frame, pos, out);
    } else {
        gemm_fallback<<<1024, 256, 0, stream>>>(seq, pe, ce, W, bias, head,
                                                frame, pos, out);
    }
}

// Round 3
// 120.001 us; speedup vs baseline: 1.3522x; 1.0666x over previous
//
#include <hip/hip_runtime.h>
#include <stdint.h>

// Bert4Argument R10: out = seq·W1 (gathered K=768 GEMM)
//                        + pe_logits[l-pos+256]        (precomputed 528x208)
//                        + ce_logits[l==pos?frame:0]   (precomputed 208x208, bias folded)
// R9 fix 1: logits prep K-split 8 waves/block + explicit reg arrays -> 4.7 waves/SIMD,
//           12 loads in flight (was ~0.7 waves/SIMD, serial loads, ~25-30us).
// R9 fix 2: gemm single-pass A: 32 rows x all 13 tiles per block (60 KB LDS),
//           A read once = 50 MB (was 2x via h-split on different XCD L2s).
// R9 fix 3: W pack only [:,0:768] (319 KB).

typedef __attribute__((ext_vector_type(8))) short short8;
typedef __attribute__((ext_vector_type(4))) float f32x4;

#define AS1 __attribute__((address_space(1)))
#define AS3 __attribute__((address_space(3)))

// ---- workspace layout ----
// Wp bf16, 13 tiles x [kb8 0..95][n16][8] = 159744 shorts (319488 B)
// pe_logits f32 [528][208] at float off 79872
// ce_logits f32 [208][208] at float off 189696 (bias folded)
#define TILE_STRIDE 12288     // shorts per n-tile (96*16*8)
#define NT         13
#define NPE_RT     33         // 33*16 = 528 rows cover 513
#define NCE_RT     13         // 13*16 = 208 rows cover 201
#define NLOG_BLK   ((NPE_RT + NCE_RT) * NT)   // 598
#define NPACK_BLK  39         // 19968 pack units / 512
#define PEL_OFF_F  79872
#define CEL_OFF_F  189696
#define WS_NEED_B  931840

__device__ __forceinline__ unsigned short f2bf(float f) {
    union { float f; unsigned int u; } v; v.f = f;
    unsigned int u = v.u;
    return (unsigned short)((u + 0x7fffu + ((u >> 16) & 1u)) >> 16);
}

__device__ __forceinline__ short8 pack8(f32x4 a, f32x4 b) {
    short8 r;
    r[0] = (short)f2bf(a.x); r[1] = (short)f2bf(a.y);
    r[2] = (short)f2bf(a.z); r[3] = (short)f2bf(a.w);
    r[4] = (short)f2bf(b.x); r[5] = (short)f2bf(b.y);
    r[6] = (short)f2bf(b.z); r[7] = (short)f2bf(b.w);
    return r;
}

__device__ __forceinline__ void dma16(const unsigned short* g, AS3 unsigned short* l) {
    __builtin_amdgcn_global_load_lds((AS1 const unsigned int*)g,
                                     (AS3 unsigned int*)l, 16, 0, 0);
}

// ---------------------------------------------------------------------------
// prep: blocks [0,598): logits. Block = one 16x16 output tile (rowtile x ntile).
//       8 waves split K=768 into 96 each (3 iters of 32), LDS reduce, wave 0 writes.
//       A and W[koff..] read f32 inline, fully unrolled reg arrays (12 loads in flight).
//       blocks [598,637): pack W[:,0:768] f32 -> bf16 13-tile layout (rows>=200 zero).
// ---------------------------------------------------------------------------
__global__ __launch_bounds__(512) void prep_kernel(
    const float* __restrict__ pe,
    const float* __restrict__ ce,
    const float* __restrict__ W,
    const float* __restrict__ bias,
    unsigned short* __restrict__ ws)
{
    __shared__ float red[8 * 256];

    if (blockIdx.x >= NLOG_BLK) {
        // ---- W pack: g = ((t*96 + kb8)*16 + n), k-range [0,768) ----
        const int g   = (blockIdx.x - NLOG_BLK) * 512 + threadIdx.x;   // < 19968 exact
        const int n   = g & 15;
        const int kb8 = (g >> 4) % 96;
        const int t   = g / 1536;
        const int row = t * 16 + n;
        const int col = kb8 * 8;
        f32x4 a = {0.f, 0.f, 0.f, 0.f}, b = {0.f, 0.f, 0.f, 0.f};
        if (row < 200) {
            const float* p = W + (size_t)row * 2304 + col;
            a = *(const f32x4*)p;
            b = *(const f32x4*)(p + 4);
        }
        *(short8*)(ws + (size_t)g * 8) = pack8(a, b);
        return;
    }

    // ---- logits ----
    const int bb   = blockIdx.x;
    const int w    = threadIdx.x >> 6;
    const int lane = threadIdx.x & 63;
    const int n16  = lane & 15;
    const int quad = lane >> 4;

    float* wsF = (float*)ws;
    int rowtile, t, nrows, koff;
    const float* A;
    float* outL;
    bool isCe;
    if (bb < NPE_RT * NT) {
        isCe = false; rowtile = bb / NT; t = bb % NT;
        nrows = 513; koff = 768;  A = pe; outL = wsF + PEL_OFF_F;
    } else {
        const int b2 = bb - NPE_RT * NT;
        isCe = true;  rowtile = b2 / NT; t = b2 % NT;
        nrows = 201; koff = 1536; A = ce; outL = wsF + CEL_OFF_F;
    }

    int arow = rowtile * 16 + n16;
    if (arow >= nrows) arow = nrows - 1;            // clamped rows never written
    const float* abase = A + (size_t)arow * 768 + w * 96 + quad * 8;

    const int col  = t * 16 + n16;                  // cols >= 200 are junk, never read
    const int wrow = (col < 200) ? col : 0;
    const float* wbase = W + (size_t)wrow * 2304 + koff + w * 96 + quad * 8;

    // all 12 loads issued before any use: one latency round-trip
    f32x4 av0[3], av1[3], wv0[3], wv1[3];
#pragma unroll
    for (int ks = 0; ks < 3; ++ks) {
        av0[ks] = *(const f32x4*)(abase + ks * 32);
        av1[ks] = *(const f32x4*)(abase + ks * 32 + 4);
        wv0[ks] = *(const f32x4*)(wbase + ks * 32);
        wv1[ks] = *(const f32x4*)(wbase + ks * 32 + 4);
    }
    f32x4 acc = (f32x4){0.f, 0.f, 0.f, 0.f};
#pragma unroll
    for (int ks = 0; ks < 3; ++ks)
        acc = __builtin_amdgcn_mfma_f32_16x16x32_bf16(
            pack8(av0[ks], av1[ks]), pack8(wv0[ks], wv1[ks]), acc, 0, 0, 0);

    // cross-wave K reduction
#pragma unroll
    for (int r = 0; r < 4; ++r)
        red[w * 256 + lane * 4 + r] = acc[r];
    __syncthreads();
    if (threadIdx.x < 64) {
        const float bv = (isCe && col < 200) ? bias[col] : 0.0f;
#pragma unroll
        for (int r = 0; r < 4; ++r) {
            float s = 0.f;
#pragma unroll
            for (int ww = 0; ww < 8; ++ww)
                s += red[ww * 256 + lane * 4 + r];
            const int row = rowtile * 16 + quad * 4 + r;
            if (row < nrows)
                outL[(size_t)row * 208 + col] = s + bv;
        }
    }
}

// ---------------------------------------------------------------------------
// Main GEMM: seq-part only, K=768 (6 chunks of 128). grid 512 x 512 thr.
// Block = 32 rows (mblk) x ALL 13 n-tiles -> A read once from HBM (50 MB).
// LDS 60 KB: A 8 slabs (fm 0..1, ks 0..3) of 64x8 bf16 at ((fm*4+ks)*64+lane)*8;
//            B 13 tiles x 2048 shorts at 4096 + t*2048 + (ks*4+quad)*128 + n16*8.
// A: gathered f32 loads issued one chunk EARLY, cvt->ds_write (1 slab/wave).
// B: dma16 from Wp, 52 units/chunk over 8 waves.
// Compute: wave w -> m-frag p=w&1, tiles q+4u (q=w>>1, u<4, t<13).
// Epilogue: + pe_logits[rel,col] + ce_logits[cls,col] (bias inside), write f32.
// ---------------------------------------------------------------------------
__global__ __launch_bounds__(512, 4) void gemm_kernel(
    const unsigned short* __restrict__ ws,
    const float* __restrict__ seq,
    const int*   __restrict__ head,
    const int*   __restrict__ frame,
    const int*   __restrict__ pos,
    float* __restrict__ out)
{
    __shared__ unsigned short lds[4096 + 13 * 2048];   // 61440 B

    const unsigned short* Wp = ws;
    const float* wsF = (const float*)ws;
    const float* peL = wsF + PEL_OFF_F;
    const float* ceL = wsF + CEL_OFF_F;

    const int tid  = threadIdx.x;
    const int wave = tid >> 6;
    const int lane = tid & 63;
    const int n16  = lane & 15;
    const int quad = lane >> 4;

    const int mblk    = blockIdx.x;          // 32 rows
    const int i       = mblk >> 3;
    const int pos_i   = pos[i];
    const int frame_i = frame[i];

    // ---- A staging: wave stages slab (fm = wave&1, sk = wave>>2... no: wave>>1) ----
    const int sfm = wave & 1;
    const int sk  = wave >> 1;               // 0..3
    const int srow = mblk * 32 + sfm * 16 + n16;
    const int hi   = head[srow];
    const float* aP = seq + ((size_t)i * 256 + hi) * 768 + sk * 32 + quad * 8;
    unsigned short* aDst = (unsigned short*)lds + ((sfm * 4 + sk) * 64 + lane) * 8;

    // ---- compute partition: p = m-frag, q -> tiles q+4u ----
    const int p = wave & 1;
    const int q = wave >> 1;
    const unsigned short* aRd = lds + p * 2048 + lane * 8;
    const unsigned short* bRd[4];
    bool uok[4];
#pragma unroll
    for (int u = 0; u < 4; ++u) {
        const int t = q + 4 * u;
        uok[u] = (t < NT);
        bRd[u] = lds + 4096 + (uok[u] ? t : 0) * 2048 + quad * 128 + n16 * 8;
    }

    f32x4 acc[4];
#pragma unroll
    for (int u = 0; u < 4; ++u)
        acc[u] = (f32x4){0.f, 0.f, 0.f, 0.f};

    // prologue: issue A loads for chunk 0
    f32x4 a0 = *(const f32x4*)(aP);
    f32x4 a1 = *(const f32x4*)(aP + 4);

    for (int cc = 0; cc < 6; ++cc) {
        // stage A (regs -> LDS) and B (dma16: 52 units over 8 waves)
        *(short8*)aDst = pack8(a0, a1);
#pragma unroll
        for (int un = wave; un < 52; un += 8) {
            const int t = un >> 2, part = un & 3;
            dma16(Wp + (size_t)t * TILE_STRIDE + cc * 2048 + part * 512 + lane * 8,
                  (AS3 unsigned short*)lds + 4096 + t * 2048 + part * 512 + lane * 8);
        }
        __syncthreads();
        // issue next chunk's A loads early: latency hides under MFMA below
        if (cc < 5) {
            const float* ap = aP + (cc + 1) * 128;
            a0 = *(const f32x4*)(ap);
            a1 = *(const f32x4*)(ap + 4);
        }
#pragma unroll
        for (int ks = 0; ks < 4; ++ks) {
            short8 af = *(const short8*)(aRd + ks * 512);
#pragma unroll
            for (int u = 0; u < 4; ++u) {
                if (uok[u]) {
                    short8 bf = *(const short8*)(bRd[u] + ks * 512);
                    acc[u] = __builtin_amdgcn_mfma_f32_16x16x32_bf16(af, bf, acc[u], 0, 0, 0);
                }
            }
        }
        __syncthreads();
    }

    // epilogue: C/D col = lane&15, row = quad*4 + r; add gathered logits
    const int rbase = mblk * 32 + p * 16 + quad * 4;
#pragma unroll
    for (int u = 0; u < 4; ++u) {
        if (uok[u]) {
            const int col = (q + 4 * u) * 16 + n16;
            if (col < 200) {
#pragma unroll
                for (int r = 0; r < 4; ++r) {
                    const int row = rbase + r;
                    const int l   = row & 255;
                    const int rel = l - pos_i + 256;
                    const int cls = (l == pos_i) ? frame_i : 0;
                    out[(size_t)row * 200 + col] =
                        acc[u][r] + peL[(size_t)rel * 208 + col]
                                  + ceL[(size_t)cls * 208 + col];
                }
            }
        }
    }
}

// ---------------------------------------------------------------------------
// Fallback (no workspace): slow but correct, f32 W converted inline.
// ---------------------------------------------------------------------------
__global__ __launch_bounds__(256) void gemm_fallback(
    const float* __restrict__ seq, const float* __restrict__ pe,
    const float* __restrict__ ce, const float* __restrict__ Wf,
    const float* __restrict__ bias, const int* __restrict__ head,
    const int* __restrict__ frame, const int* __restrict__ pos,
    float* __restrict__ out)
{
    const int tid  = threadIdx.x;
    const int wave = tid >> 6;
    const int lane = tid & 63;
    const int n16  = lane & 15;
    const int quad = lane >> 4;

    const int mrow  = blockIdx.x * 16 + n16;
    const int i     = mrow >> 8;
    const int j     = mrow & 255;
    const int pos_i = pos[i];
    const int hi    = head[mrow];
    const int rel   = j - pos_i + 256;
    const int cls   = (j == pos_i) ? frame[i] : 0;

    const float* segs[3];
    segs[0] = seq + ((size_t)i * 256 + (size_t)hi) * 768 + quad * 8;
    segs[1] = pe + (size_t)rel * 768 + quad * 8;
    segs[2] = ce + (size_t)cls * 768 + quad * 8;

    const int ntl = (wave == 0) ? 4 : 3;
    f32x4 acc[4];
#pragma unroll
    for (int u = 0; u < 4; ++u) {
        const int t = wave + 4 * u;
        const int col = t * 16 + n16;
        const float bv = (t < 13 && col < 200) ? bias[col] : 0.0f;
        acc[u] = (f32x4){bv, bv, bv, bv};
    }

    for (int s = 0; s < 3; ++s) {
        const float* ap = segs[s];
#pragma unroll 2
        for (int kk = 0; kk < 768; kk += 32) {
            short8 afr = pack8(*(const f32x4*)(ap + kk), *(const f32x4*)(ap + kk + 4));
#pragma unroll
            for (int u = 0; u < 4; ++u) {
                if (u < ntl) {
                    const int t = wave + 4 * u;
                    const int row = t * 16 + n16;
                    short8 bfr = {0, 0, 0, 0, 0, 0, 0, 0};
                    if (row < 200) {
                        const float* qp = Wf + (size_t)row * 2304 + s * 768 + kk + quad * 8;
                        bfr = pack8(*(const f32x4*)qp, *(const f32x4*)(qp + 4));
                    }
                    acc[u] = __builtin_amdgcn_mfma_f32_16x16x32_bf16(afr, bfr, acc[u], 0, 0, 0);
                }
            }
        }
    }

    const int rbase = blockIdx.x * 16 + quad * 4;
#pragma unroll
    for (int u = 0; u < 4; ++u) {
        const int t = wave + 4 * u;
        if (t < 13) {
            const int col = t * 16 + n16;
            if (col < 200) {
#pragma unroll
                for (int r = 0; r < 4; ++r)
                    out[(size_t)(rbase + r) * 200 + col] = acc[u][r];
            }
        }
    }
}

// ---------------------------------------------------------------------------
extern "C" void kernel_launch(void* const* d_in, const int* in_sizes, int n_in,
                              void* d_out, int out_size, void* d_ws, size_t ws_size,
                              hipStream_t stream) {
    const float* seq  = (const float*)d_in[0];
    const float* pe   = (const float*)d_in[1];
    const float* ce   = (const float*)d_in[2];
    const float* W    = (const float*)d_in[3];
    const float* bias = (const float*)d_in[4];
    const int* head   = (const int*)d_in[5];
    const int* frame  = (const int*)d_in[6];
    const int* pos    = (const int*)d_in[7];
    float* out = (float*)d_out;

    if (d_ws != nullptr && ws_size >= (size_t)WS_NEED_B) {
        unsigned short* ws = (unsigned short*)d_ws;
        prep_kernel<<<NLOG_BLK + NPACK_BLK, 512, 0, stream>>>(pe, ce, W, bias, ws);
        gemm_kernel<<<512, 512, 0, stream>>>(ws, seq, head, frame, pos, out);
    } else {
        gemm_fallback<<<1024, 256, 0, stream>>>(seq, pe, ce, W, bias, head,
                                                frame, pos, out);
    }
}